// Round 5
// baseline (916.727 us; speedup 1.0000x reference)
//
#include <hip/hip_runtime.h>

// Fused RNN: encoders + 576-step LSTM + projection + softmax.
// 256 blocks x 256 threads (4 waves = 1 wave/SIMD), 4 batches/block.
// Latency-bound: kernel time = 576 x (barrier-to-barrier critical path).
//
// Round-11: ONE wave per SIMD + transcendental diet.
//  - Evidence (R7-R10): per-step busy cycles are ~constant (MFMA ~450,
//    VALU ~700 of 1867); with 2 phase-locked waves/SIMD both burst MFMA
//    then both burst VALU -> serialized. A single wave per SIMD lets the
//    compiler pack its activation VALU into its own MFMA issue-stall
//    shadow (deps allow: pass-0 acts need only tiles 0..3; they overlap
//    tile 4..6 MFMAs). Also: barrier 8->4 waves, B-reads 32->16.
//  - Tiles: w0:0-6, w1:7-12(+staging), w2:13-19, w3:20-24+proj(+softmax).
//    Two activation passes/wave (pass0 = tiles 0..3, pass1 = rest).
//  - Trans diet: gate columns pre-scaled at frag init by -log2e (i,f,o),
//    -2log2e (g), +log2e (proj) -> v_exp_f32 without the mul; merged
//    reciprocals: gi*gg = (1-B)/((1+A)(1+B)), go*tanh(c) = (1-C)/((1+O)(1+C)).
//    10 trans -> 8, -5 muls per (unit,batch).
//  - Keeps: LDS-only barrier (no vmcnt drain), D-fragment==activation
//    layout, reg-held encoder weights, distance-2 staging prefetch,
//    exp-no-max-subtract softmax.

#define NTHR 256
#define L2E 1.4426950408889634f

typedef _Float16 half8 __attribute__((ext_vector_type(8)));
typedef float    f32x4 __attribute__((ext_vector_type(4)));

struct __align__(16) SM {
  _Float16 Y[2][4][144];   // [phase][batch][k]: h(0..99), x(100..108), 1(109), 0(110..143)
};

__device__ __forceinline__ float fexp2(float x) {
#if defined(__has_builtin)
#if __has_builtin(__builtin_amdgcn_exp2f)
  return __builtin_amdgcn_exp2f(x);
#else
  return __builtin_exp2f(x);
#endif
#else
  return __builtin_exp2f(x);
#endif
}

// W~ row k of column n: k<100 -> W_h, 100..108 -> W_x, 109 -> b_lstm, else 0.
__device__ __forceinline__ float wld(int k, int n,
                                     const float* __restrict__ Wh,
                                     const float* __restrict__ Wx,
                                     const float* __restrict__ bl) {
  if (k < 100)  return Wh[k * 400 + n];
  if (k < 109)  return Wx[(k - 100) * 400 + n];
  if (k == 109) return bl[n];
  return 0.f;
}

// Projection column m (out-dim): rows = h, bias at 109, zeros elsewhere.
__device__ __forceinline__ float wproj(int k, int m,
                                       const float* __restrict__ Wo,
                                       const float* __restrict__ bo) {
  if (m >= 9)   return 0.f;
  if (k < 100)  return Wo[k * 9 + m];
  if (k == 109) return bo[m];
  return 0.f;
}

// LDS-only barrier: do NOT drain vmcnt (global prefetch/stores stay in flight).
__device__ __forceinline__ void sync_lds() {
  asm volatile("s_waitcnt lgkmcnt(0)" ::: "memory");
  __builtin_amdgcn_s_barrier();
  asm volatile("" ::: "memory");
}

// butterfly-add over 16-lane groups (ds_swizzle xor patterns, compile-time)
#define SWZ_ADD(s, pat) \
  (s) += __uint_as_float(__builtin_amdgcn_ds_swizzle(__float_as_uint(s), (pat)))

__global__ __launch_bounds__(NTHR, 1)
void lstm_fused(const float* __restrict__ g_input,
                const float* __restrict__ g_task,
                const float* __restrict__ g_Win,
                const float* __restrict__ g_bin,
                const float* __restrict__ g_Wtask,
                const float* __restrict__ g_btask,
                const float* __restrict__ g_Wx,
                const float* __restrict__ g_Wh,
                const float* __restrict__ g_bl,
                const float* __restrict__ g_Wout,
                const float* __restrict__ g_bout,
                float* __restrict__ g_out)
{
  __shared__ SM L;
  const int tid  = threadIdx.x;
  const int bg0  = blockIdx.x * 4;
  const int wv   = tid >> 6;        // wave id 0..3 (one per SIMD)
  const int lane = tid & 63;
  const int q    = lane >> 4;       // MFMA k-quad
  const int nl   = lane & 15;       // A row m / B-D col n
  const int hi   = lane >> 4;       // D row group (unit-in-tile)
  const int xr_  = nl >> 2;         // replica -> tile select
  const int ab   = nl & 3;          // batch

  // ---- cooperative LDS fill: Y = 0 except k==109 -> 1.0 (bias slot) ----
  for (int i = tid; i < 2 * 4 * 144; i += NTHR)
    ((_Float16*)L.Y)[i] = ((i % 144) == 109) ? (_Float16)1.f : (_Float16)0.f;

  // ---- tile ownership: rec tiles w0:0-6, w1:7-12, w2:13-19, w3:20-24+proj ----
  const int NTF   = (wv == 0 || wv == 2) ? 7 : 6;   // fragment slots (w3: 5 rec + proj)
  const int NR    = (wv == 3) ? 5 : NTF;            // recurrent tiles
  const int rem   = NR - 4;                         // pass-1 tiles (3,2,3,1)
  const int tbase = (wv == 0) ? 0 : (wv == 1) ? 7 : (wv == 2) ? 13 : 20;

  // ---- A-fragments: weights, reg-stationary, PRE-SCALED for exp2 ----
  // m = nl = 4*Uin + gate; column n = gate*100 + (tbase+ti)*4 + Uin.
  // scale: i,f,o gates -log2e; g gate -2log2e; proj +log2e.
  half8 Af[7][4];   // [ti][kc]; lane holds A[m=nl][k=kc*32+q*8+j]
  {
    const int gate = ab;
    const int Uin  = xr_;
    const float scl = (gate == 2) ? (-2.f * L2E) : (-L2E);
#pragma unroll
    for (int ti = 0; ti < 7; ++ti) {
      if (ti < NTF) {
        const bool proj = (wv == 3 && ti == 5);
        const int n = gate * 100 + (tbase + ti) * 4 + Uin;
#pragma unroll
        for (int kc = 0; kc < 4; ++kc) {
#pragma unroll
          for (int j = 0; j < 8; ++j) {
            const int k = kc * 32 + q * 8 + j;
            Af[ti][kc][j] = (_Float16)(proj ? wproj(k, nl, g_Wout, g_bout) * L2E
                                            : wld(k, n, g_Wh, g_Wx, g_bl) * scl);
          }
        }
      }
    }
  }

  float c0 = 0.f, c1 = 0.f;   // c_state for pass 0 / pass 1

  // ---- wave-1 staging role: lanes 28..63 -> 36 items (b = sl/9, f = sl%9) ----
  const int sl  = lane - 28;
  const int stb = (sl >= 0) ? sl / 9 : 0;
  const int stf = (sl >= 0) ? sl % 9 : 0;
  float we_in[9], we_task[9], be_in = 0.f, be_task = 0.f;
  if (wv == 1) {
#pragma unroll
    for (int ff = 0; ff < 9; ++ff) {
      we_in[ff]   = g_Win[ff * 9 + stf];
      we_task[ff] = g_Wtask[ff * 9 + stf];
    }
    be_in = g_bin[stf]; be_task = g_btask[stf];
  }
  float xrA[9], xrB[9];   // prefetch buffers: xrB = odd times, xrA = even times

  auto LOADX = [&](float* xr, int tt) {
    const float* src = (tt < 512)
      ? g_input + ((long)(bg0 + stb) * 512 + tt) * 9
      : g_task  + ((long)(bg0 + stb) * 64 + (tt - 512)) * 9;
#pragma unroll
    for (int ff = 0; ff < 9; ++ff) xr[ff] = src[ff];
  };
  auto ENC9 = [&](const float* xr, const float (&w)[9], float b) -> float {
    float a0 = b, a1 = 0.f, a2 = 0.f;
    a0 = fmaf(xr[0], w[0], a0); a1 = fmaf(xr[1], w[1], a1); a2 = fmaf(xr[2], w[2], a2);
    a0 = fmaf(xr[3], w[3], a0); a1 = fmaf(xr[4], w[4], a1); a2 = fmaf(xr[5], w[5], a2);
    a0 = fmaf(xr[6], w[6], a0); a1 = fmaf(xr[7], w[7], a1); a2 = fmaf(xr[8], w[8], a2);
    return (a0 + a1) + a2;
  };
  auto ENCSTEP = [&](const float* xr, int tt) {
    float a;
    if (tt < 512) a = ENC9(xr, we_in, be_in);
    else          a = ENC9(xr, we_task, be_task);
    L.Y[tt & 1][stb][100 + stf] = (_Float16)fmaxf(a, 0.f);
  };
  // activation: zv pre-scaled so exp2 is direct; merged reciprocals.
  auto ACT = [&](int p, const float* zv, int aUx, float& c) {
    const float A = fexp2(zv[0]);                 // e^{-zi}
    const float F = fexp2(zv[1]);                 // e^{-zf}
    const float B = fexp2(zv[2]);                 // e^{-2 zg}
    const float O = fexp2(zv[3]);                 // e^{-zo}
    const float gf = __builtin_amdgcn_rcpf(1.f + F);
    const float ig = (1.f - B) * __builtin_amdgcn_rcpf((1.f + A) * (1.f + B));
    c = fmaf(gf, c, ig);
    const float C = fexp2(fmaxf(c, -30.f) * (-2.f * L2E));   // e^{-2c}
    const float h = (1.f - C) * __builtin_amdgcn_rcpf((1.f + O) * (1.f + C));
    L.Y[p ^ 1][ab][aUx] = (_Float16)h;
  };
  // softmax over the projection D-fragment (xr_==3 lanes hold logits[4hi+r][ab])
  auto SMAX = [&](f32x4 v, int tout) {
    float e0 = fexp2(v[0]), e1 = fexp2(v[1]), e2 = fexp2(v[2]), e3 = fexp2(v[3]);
    if (hi == 2) { e1 = 0.f; e2 = 0.f; e3 = 0.f; }
    if (hi == 3) { e0 = 0.f; e1 = 0.f; e2 = 0.f; e3 = 0.f; }
    const float pl = (e0 + e1) + (e2 + e3);
    const float s1 = pl + __uint_as_float(__builtin_amdgcn_ds_swizzle(__float_as_uint(pl), 0x401F));
    const float ss = s1 + __shfl_xor(s1, 32, 64);
    const float rs = __builtin_amdgcn_rcpf(ss);
    if (hi < 3) {
      float* dst = g_out + ((long)(bg0 + ab) * 576 + tout) * 9 + 4 * hi;
      dst[0] = e0 * rs;
      if (hi < 2) { dst[1] = e1 * rs; dst[2] = e2 * rs; dst[3] = e3 * rs; }
    }
  };

  sync_lds();   // Y zero-fill visible

  // ---- prologue (wave 1): stage encoded s_0 into Y[0]; prefetch x(1),x(2) ----
  if (wv == 1 && sl >= 0) {
    float x0[9];
    LOADX(x0, 0);
    L.Y[0][stb][100 + stf] = (_Float16)fmaxf(ENC9(x0, we_in, be_in), 0.f);
    LOADX(xrB, 1);
    LOADX(xrA, 2);
  }
  sync_lds();

  // ---- main recurrence: ONE LDS-only barrier per step ----
  for (int t = 0; t < 576; ++t) {
    const int p = t & 1;
    // -- B-operand: y rows, n = 4x+b -> each lane reads batch ab --
    half8 Bv[4];
#pragma unroll
    for (int kc = 0; kc < 4; ++kc)
      Bv[kc] = *(const half8*)&L.Y[p][ab][kc * 32 + q * 8];
    // -- GEMM on matrix pipe (tiles 0..3 first: pass-0 acts can overlap rest) --
    f32x4 acc[7];
#pragma unroll
    for (int ti = 0; ti < 7; ++ti) {
      if (ti < NTF) {
        acc[ti] = (f32x4)0.f;
#pragma unroll
        for (int kc = 0; kc < 4; ++kc)
          acc[ti] = __builtin_amdgcn_mfma_f32_16x16x32_f16(Af[ti][kc], Bv[kc], acc[ti], 0, 0, 0);
      }
    }
    // -- activation pass 0: tiles tbase+0..3, replica xr_ selects tile --
    {
      float zv[4];
#pragma unroll
      for (int g = 0; g < 4; ++g) {
        const float a01 = (xr_ == 0) ? acc[0][g] : acc[1][g];
        const float a23 = (xr_ == 2) ? acc[2][g] : acc[3][g];
        zv[g] = (xr_ < 2) ? a01 : a23;
      }
      ACT(p, zv, (tbase + xr_) * 4 + hi, c0);
    }
    // -- activation pass 1: tiles tbase+4.. (rem = 3,2,3,1) --
    if (xr_ < rem) {
      float zv[4];
#pragma unroll
      for (int g = 0; g < 4; ++g) {
        if (rem == 3)      zv[g] = (xr_ == 0) ? acc[4][g] : ((xr_ == 1) ? acc[5][g] : acc[6][g]);
        else if (rem == 2) zv[g] = (xr_ == 0) ? acc[4][g] : acc[5][g];
        else               zv[g] = acc[4][g];
      }
      ACT(p, zv, (tbase + 4 + xr_) * 4 + hi, c1);
    }
    // -- softmax (wave 3, xr_==3 lanes): logits of h[t-1] in acc[5] --
    if (wv == 3 && xr_ == 3 && t > 0) SMAX(acc[5], t - 1);
    // -- staging (wave 1): consume prefetched x(t+1), refill with x(t+3) --
    if (wv == 1 && sl >= 0 && t + 1 < 576) {
      if (t & 1) { ENCSTEP(xrA, t + 1); if (t + 3 < 576) LOADX(xrA, t + 3); }
      else       { ENCSTEP(xrB, t + 1); if (t + 3 < 576) LOADX(xrB, t + 3); }
    }
    sync_lds();
  }

  // ---- tail: projection + softmax for t=575 (h[575] in Y[0]) ----
  if (wv == 3) {
    half8 Bv[4];
#pragma unroll
    for (int kc = 0; kc < 4; ++kc)
      Bv[kc] = *(const half8*)&L.Y[0][ab][kc * 32 + q * 8];
    f32x4 a2 = (f32x4)0.f;
#pragma unroll
    for (int kc = 0; kc < 4; ++kc)
      a2 = __builtin_amdgcn_mfma_f32_16x16x32_f16(Af[5][kc], Bv[kc], a2, 0, 0, 0);
    if (xr_ == 3) SMAX(a2, 575);
  }
}

extern "C" void kernel_launch(void* const* d_in, const int* in_sizes, int n_in,
                              void* d_out, int out_size, void* d_ws, size_t ws_size,
                              hipStream_t stream) {
  const float* input  = (const float*)d_in[0];
  const float* task   = (const float*)d_in[1];
  const float* W_in   = (const float*)d_in[2];
  const float* b_in   = (const float*)d_in[3];
  const float* W_task = (const float*)d_in[4];
  const float* b_task = (const float*)d_in[5];
  const float* W_x    = (const float*)d_in[6];
  const float* W_h    = (const float*)d_in[7];
  const float* b_lstm = (const float*)d_in[8];
  const float* W_out  = (const float*)d_in[9];
  const float* b_out  = (const float*)d_in[10];
  float* out = (float*)d_out;

  lstm_fused<<<256, NTHR, 0, stream>>>(input, task, W_in, b_in, W_task, b_task,
                                       W_x, W_h, b_lstm, W_out, b_out, out);
}

// Round 6
// 520.255 us; speedup vs baseline: 1.7621x; 1.7621x over previous
//
#include <hip/hip_runtime.h>

// Fused RNN: encoders + 576-step LSTM + projection + softmax.
// 256 blocks x 512 threads (8 waves = 2/SIMD), 4 batches/block.
// Latency-bound: kernel time = 576 x (barrier-to-barrier critical path).
//
// Round-12: REVERT to round-10 structure (R11's 1-wave/SIMD exposed all
// dependency stalls on in-order SIMDs: 917us. 2 phase-locked waves/SIMD
// provide the MFMA<->VALU overlap, m114-style). Grafts from R11:
//  - Transcendental diet (numerically validated in R11): gate columns
//    pre-scaled at frag init by -log2e (i,f,o), -2log2e (g), +log2e (proj)
//    -> bare v_exp_f32; merged reciprocals gi*gg=(1-B)/((1+A)(1+B)),
//    go*tanh(c)=(1-C)/((1+O)(1+C)); c clamped at -30 to avoid exp2 overflow.
//  - Tile rebalance 4,4,4,3,3,3,2,2(+proj): staging wave (6) and softmax
//    wave (7) carry only 2 recurrent tiles (they are the per-phase poles).
//  - Calibration note (m06 recalc): one 16x16x32_f16 MFMA = ~19cy of SIMD
//    matrix pipe -> 26 MFMA/SIMD/step = ~505cy. MfmaUtil 24% checks out.
//    VALU (739cy) is the reducible term this round targets.
//  - Keeps: LDS-only barrier (no vmcnt drain), proj-as-MFMA-tile,
//    D-fragment==activation layout, reg-held encoder weights, distance-2
//    staging prefetch, exp-no-max-subtract softmax.

#define NTHR 512
#define L2E 1.4426950408889634f

typedef _Float16 half8 __attribute__((ext_vector_type(8)));
typedef float    f32x4 __attribute__((ext_vector_type(4)));

struct __align__(16) SM {
  _Float16 Y[2][4][144];   // [phase][batch][k]: h(0..99), x(100..108), 1(109), 0(110..143)
};

__device__ __forceinline__ float fexp2(float x) {
#if defined(__has_builtin)
#if __has_builtin(__builtin_amdgcn_exp2f)
  return __builtin_amdgcn_exp2f(x);
#else
  return __builtin_exp2f(x);
#endif
#else
  return __builtin_exp2f(x);
#endif
}

// W~ row k of column n: k<100 -> W_h, 100..108 -> W_x, 109 -> b_lstm, else 0.
__device__ __forceinline__ float wld(int k, int n,
                                     const float* __restrict__ Wh,
                                     const float* __restrict__ Wx,
                                     const float* __restrict__ bl) {
  if (k < 100)  return Wh[k * 400 + n];
  if (k < 109)  return Wx[(k - 100) * 400 + n];
  if (k == 109) return bl[n];
  return 0.f;
}

// Projection column m (out-dim): rows = h, bias at 109, zeros elsewhere.
__device__ __forceinline__ float wproj(int k, int m,
                                       const float* __restrict__ Wo,
                                       const float* __restrict__ bo) {
  if (m >= 9)   return 0.f;
  if (k < 100)  return Wo[k * 9 + m];
  if (k == 109) return bo[m];
  return 0.f;
}

// LDS-only barrier: do NOT drain vmcnt (global prefetch/stores stay in flight).
__device__ __forceinline__ void sync_lds() {
  asm volatile("s_waitcnt lgkmcnt(0)" ::: "memory");
  __builtin_amdgcn_s_barrier();
  asm volatile("" ::: "memory");
}

__global__ __launch_bounds__(NTHR, 1)
void lstm_fused(const float* __restrict__ g_input,
                const float* __restrict__ g_task,
                const float* __restrict__ g_Win,
                const float* __restrict__ g_bin,
                const float* __restrict__ g_Wtask,
                const float* __restrict__ g_btask,
                const float* __restrict__ g_Wx,
                const float* __restrict__ g_Wh,
                const float* __restrict__ g_bl,
                const float* __restrict__ g_Wout,
                const float* __restrict__ g_bout,
                float* __restrict__ g_out)
{
  __shared__ SM L;
  const int tid  = threadIdx.x;
  const int bg0  = blockIdx.x * 4;
  const int wv   = tid >> 6;        // wave id 0..7
  const int lane = tid & 63;
  const int q    = lane >> 4;       // MFMA k-quad
  const int nl   = lane & 15;       // A row m / B-D col n
  const int hi   = lane >> 4;       // D row group (unit-in-tile)
  const int xr_  = nl >> 2;         // replica -> tile select
  const int ab   = nl & 3;          // batch

  // ---- cooperative LDS fill: Y = 0 except k==109 -> 1.0 (bias slot) ----
  for (int i = tid; i < 2 * 4 * 144; i += NTHR)
    ((_Float16*)L.Y)[i] = ((i % 144) == 109) ? (_Float16)1.f : (_Float16)0.f;

  // ---- tile ownership: 4,4,4,3,3,3,2,2(+proj) = 25 rec tiles + proj ----
  const int NR    = (wv < 3) ? 4 : (wv < 6) ? 3 : 2;       // recurrent tiles
  const int NTF   = (wv == 7) ? 3 : NR;                    // fragment slots
  const int tbase = (wv < 3) ? wv * 4
                  : (wv < 6) ? 12 + (wv - 3) * 3
                  : (wv == 6) ? 21 : 23;

  // ---- A-fragments: weights, reg-stationary, PRE-SCALED for exp2 ----
  // m = nl = 4*Uin + gate; column n = gate*100 + (tbase+ti)*4 + Uin.
  half8 Af[4][4];   // [ti][kc]; lane holds A[m=nl][k=kc*32+q*8+j]
  {
    const int gate = ab;
    const int Uin  = xr_;
    const float scl = (gate == 2) ? (-2.f * L2E) : (-L2E);
#pragma unroll
    for (int ti = 0; ti < 4; ++ti) {
      if (ti < NTF) {
        const bool proj = (wv == 7 && ti == 2);
        const int n = gate * 100 + (tbase + ti) * 4 + Uin;
#pragma unroll
        for (int kc = 0; kc < 4; ++kc) {
#pragma unroll
          for (int j = 0; j < 8; ++j) {
            const int k = kc * 32 + q * 8 + j;
            Af[ti][kc][j] = (_Float16)(proj ? wproj(k, nl, g_Wout, g_bout) * L2E
                                            : wld(k, n, g_Wh, g_Wx, g_bl) * scl);
          }
        }
      }
    }
  }

  // ---- activation ownership: lane (x,hi,b) -> unit (tbase+min(x,NR-1))*4+hi ----
  const int aU = (tbase + ((xr_ < NR) ? xr_ : NR - 1)) * 4 + hi;
  float c_state = 0.f;

  // ---- wave-6 staging role: lanes 28..63 -> 36 items (b = sl/9, f = sl%9) ----
  const int sl  = lane - 28;
  const int stb = (sl >= 0) ? sl / 9 : 0;
  const int stf = (sl >= 0) ? sl % 9 : 0;
  float we_in[9], we_task[9], be_in = 0.f, be_task = 0.f;
  if (wv == 6) {
#pragma unroll
    for (int ff = 0; ff < 9; ++ff) {
      we_in[ff]   = g_Win[ff * 9 + stf];
      we_task[ff] = g_Wtask[ff * 9 + stf];
    }
    be_in = g_bin[stf]; be_task = g_btask[stf];
  }
  float xrA[9], xrB[9];   // prefetch buffers: xrB = odd times, xrA = even times

  auto LOADX = [&](float* xr, int tt) {
    const float* src = (tt < 512)
      ? g_input + ((long)(bg0 + stb) * 512 + tt) * 9
      : g_task  + ((long)(bg0 + stb) * 64 + (tt - 512)) * 9;
#pragma unroll
    for (int ff = 0; ff < 9; ++ff) xr[ff] = src[ff];
  };
  auto ENC9 = [&](const float* xr, const float (&w)[9], float b) -> float {
    float a0 = b, a1 = 0.f, a2 = 0.f;
    a0 = fmaf(xr[0], w[0], a0); a1 = fmaf(xr[1], w[1], a1); a2 = fmaf(xr[2], w[2], a2);
    a0 = fmaf(xr[3], w[3], a0); a1 = fmaf(xr[4], w[4], a1); a2 = fmaf(xr[5], w[5], a2);
    a0 = fmaf(xr[6], w[6], a0); a1 = fmaf(xr[7], w[7], a1); a2 = fmaf(xr[8], w[8], a2);
    return (a0 + a1) + a2;
  };
  auto ENCSTEP = [&](const float* xr, int tt) {
    float a;
    if (tt < 512) a = ENC9(xr, we_in, be_in);
    else          a = ENC9(xr, we_task, be_task);
    L.Y[tt & 1][stb][100 + stf] = (_Float16)fmaxf(a, 0.f);
  };
  // activation: zv pre-scaled so exp2 is direct; merged reciprocals.
  auto ACT = [&](int p, const float* zv) {
    const float A = fexp2(zv[0]);                 // e^{-zi}
    const float F = fexp2(zv[1]);                 // e^{-zf}
    const float B = fexp2(zv[2]);                 // e^{-2 zg}
    const float O = fexp2(zv[3]);                 // e^{-zo}
    const float gf = __builtin_amdgcn_rcpf(1.f + F);
    const float ig = (1.f - B) * __builtin_amdgcn_rcpf((1.f + A) * (1.f + B));
    c_state = fmaf(gf, c_state, ig);
    const float C = fexp2(fmaxf(c_state, -30.f) * (-2.f * L2E));   // e^{-2c}
    const float h = (1.f - C) * __builtin_amdgcn_rcpf((1.f + O) * (1.f + C));
    L.Y[p ^ 1][ab][aU] = (_Float16)h;
  };
  // softmax over the projection D-fragment (wave-7 xr_==2 lanes hold
  // logits[4hi+r][ab], pre-scaled by log2e -> fexp2 direct)
  auto SMAX = [&](f32x4 v, int tout) {
    float e0 = fexp2(v[0]), e1 = fexp2(v[1]), e2 = fexp2(v[2]), e3 = fexp2(v[3]);
    if (hi == 2) { e1 = 0.f; e2 = 0.f; e3 = 0.f; }
    if (hi == 3) { e0 = 0.f; e1 = 0.f; e2 = 0.f; e3 = 0.f; }
    const float pl = (e0 + e1) + (e2 + e3);
    const float s1 = pl + __uint_as_float(__builtin_amdgcn_ds_swizzle(__float_as_uint(pl), 0x401F));
    const float ss = s1 + __shfl_xor(s1, 32, 64);
    const float rs = __builtin_amdgcn_rcpf(ss);
    if (hi < 3) {
      float* dst = g_out + ((long)(bg0 + ab) * 576 + tout) * 9 + 4 * hi;
      dst[0] = e0 * rs;
      if (hi < 2) { dst[1] = e1 * rs; dst[2] = e2 * rs; dst[3] = e3 * rs; }
    }
  };

  sync_lds();   // Y zero-fill visible

  // ---- prologue (wave 6): stage encoded s_0 into Y[0]; prefetch x(1),x(2) ----
  if (wv == 6 && sl >= 0) {
    float x0[9];
    LOADX(x0, 0);
    L.Y[0][stb][100 + stf] = (_Float16)fmaxf(ENC9(x0, we_in, be_in), 0.f);
    LOADX(xrB, 1);
    LOADX(xrA, 2);
  }
  sync_lds();

  // ---- main recurrence: ONE LDS-only barrier per step ----
  for (int t = 0; t < 576; ++t) {
    const int p = t & 1;
    // -- B-operand: y rows, n = 4x+b -> each lane reads batch ab --
    half8 Bv[4];
#pragma unroll
    for (int kc = 0; kc < 4; ++kc)
      Bv[kc] = *(const half8*)&L.Y[p][ab][kc * 32 + q * 8];
    // -- GEMM on matrix pipe (incl. projection tile on wave 7) --
    f32x4 acc[4];
#pragma unroll
    for (int ti = 0; ti < 4; ++ti) {
      if (ti < NTF) {
        acc[ti] = (f32x4)0.f;
#pragma unroll
        for (int kc = 0; kc < 4; ++kc)
          acc[ti] = __builtin_amdgcn_mfma_f32_16x16x32_f16(Af[ti][kc], Bv[kc], acc[ti], 0, 0, 0);
      }
    }
    // -- save wave-7 projection result before the select-clamp --
    f32x4 pacc;
    if (wv == 7) pacc = acc[2];
    // -- clamp acc for the uniform 3-cndmask select (dup writes benign) --
    if (NR == 2) { acc[2] = acc[1]; acc[3] = acc[1]; }
    if (NR == 3) { acc[3] = acc[2]; }
    // -- replica x selects its tile --
    float zv[4];
#pragma unroll
    for (int g = 0; g < 4; ++g) {
      const float a01 = (xr_ == 0) ? acc[0][g] : acc[1][g];
      const float a23 = (xr_ == 2) ? acc[2][g] : acc[3][g];
      zv[g] = (xr_ < 2) ? a01 : a23;
    }
    // -- post-GEMM roles --
    if (wv < 7) {
      ACT(p, zv);                                  // all lanes (clamped dups ok)
    } else if (xr_ < 2) {
      ACT(p, zv);                                  // wave-7 rec tiles 23,24
    } else if (xr_ == 2 && t > 0) {
      SMAX(pacc, t - 1);                           // logits of h[t-1]
    }
    // -- staging (wave 6): consume prefetched x(t+1), refill with x(t+3) --
    if (wv == 6 && sl >= 0 && t + 1 < 576) {
      if (t & 1) { ENCSTEP(xrA, t + 1); if (t + 3 < 576) LOADX(xrA, t + 3); }
      else       { ENCSTEP(xrB, t + 1); if (t + 3 < 576) LOADX(xrB, t + 3); }
    }
    sync_lds();
  }

  // ---- tail: projection + softmax for t=575 (h[575] in Y[0]) ----
  if (wv == 7) {
    half8 Bv[4];
#pragma unroll
    for (int kc = 0; kc < 4; ++kc)
      Bv[kc] = *(const half8*)&L.Y[0][ab][kc * 32 + q * 8];
    f32x4 a2 = (f32x4)0.f;
#pragma unroll
    for (int kc = 0; kc < 4; ++kc)
      a2 = __builtin_amdgcn_mfma_f32_16x16x32_f16(Af[2][kc], Bv[kc], a2, 0, 0, 0);
    if (xr_ == 2) SMAX(a2, 575);
  }
}

extern "C" void kernel_launch(void* const* d_in, const int* in_sizes, int n_in,
                              void* d_out, int out_size, void* d_ws, size_t ws_size,
                              hipStream_t stream) {
  const float* input  = (const float*)d_in[0];
  const float* task   = (const float*)d_in[1];
  const float* W_in   = (const float*)d_in[2];
  const float* b_in   = (const float*)d_in[3];
  const float* W_task = (const float*)d_in[4];
  const float* b_task = (const float*)d_in[5];
  const float* W_x    = (const float*)d_in[6];
  const float* W_h    = (const float*)d_in[7];
  const float* b_lstm = (const float*)d_in[8];
  const float* W_out  = (const float*)d_in[9];
  const float* b_out  = (const float*)d_in[10];
  float* out = (float*)d_out;

  lstm_fused<<<256, NTHR, 0, stream>>>(input, task, W_in, b_in, W_task, b_task,
                                       W_x, W_h, b_lstm, W_out, b_out, out);
}

// Round 7
// 437.270 us; speedup vs baseline: 2.0965x; 1.1898x over previous
//
#include <hip/hip_runtime.h>

// Fused RNN: encoders + 576-step LSTM + projection + softmax.
// 256 blocks x 1024 threads (16 waves = 4/SIMD), 4 batches/block, 1 block/CU.
// Latency-bound: kernel time = 576 x (barrier-to-barrier critical path).
//
// Round-13: 16 thin waves -> per-wave chain halved, 4-way stall filling.
//  - Evidence: R9 (Z-elim) ~0, R12 (VALU diet) -9% => critical path is the
//    exposed per-wave chain {ds_read B -> chained MFMAs -> ACT -> ds_write ->
//    barrier}, not pipe throughput and not VALU volume. Work/SIMD is fixed
//    (26 MFMA = ~505cy matrix pipe); per-wave chain length is not.
//  - 16 waves x <=2 tiles: slowest wave = 8 MFMA + 2 ACT (was 16 + 4);
//    4 waves/SIMD interleave on the in-order SIMD (R11 showed 1/SIMD is a
//    disaster; 2/SIMD was R10; this extends the proven direction).
//  - Tiles: w0..11 -> 2 each (tiles 0..23), w12 -> tile 24, w15 -> proj tile,
//    w14 -> encoder staging, w13 idle. SIMD MFMA loads 28/24/24/28.
//  - Numerics reverted to R10 exact (fast_sigmoid/fast_tanh/__expf ACT+SMAX;
//    R12's merged-reciprocal diet withdrawn: longer serial chain, -9%).
//  - Keeps: LDS-only barrier (no vmcnt drain), proj-as-MFMA-tile,
//    D-fragment==activation layout, reg-held encoder weights, distance-2
//    staging prefetch, exp-no-max-subtract softmax, padded Y (stride 144).

#define NTHR 1024

typedef _Float16 half8 __attribute__((ext_vector_type(8)));
typedef float    f32x4 __attribute__((ext_vector_type(4)));

struct __align__(16) SM {
  _Float16 Y[2][4][144];   // [phase][batch][k]: h(0..99), x(100..108), 1(109), 0(110..143)
};

__device__ __forceinline__ float fast_sigmoid(float x) {
  return __builtin_amdgcn_rcpf(1.f + __expf(-x));
}
__device__ __forceinline__ float fast_tanh(float x) {
  return fmaf(2.f, __builtin_amdgcn_rcpf(1.f + __expf(-2.f * x)), -1.f);
}

// W~ row k of column n: k<100 -> W_h, 100..108 -> W_x, 109 -> b_lstm, else 0.
__device__ __forceinline__ float wld(int k, int n,
                                     const float* __restrict__ Wh,
                                     const float* __restrict__ Wx,
                                     const float* __restrict__ bl) {
  if (k < 100)  return Wh[k * 400 + n];
  if (k < 109)  return Wx[(k - 100) * 400 + n];
  if (k == 109) return bl[n];
  return 0.f;
}

// Projection column m (out-dim): rows = h, bias at 109, zeros elsewhere.
__device__ __forceinline__ float wproj(int k, int m,
                                       const float* __restrict__ Wo,
                                       const float* __restrict__ bo) {
  if (m >= 9)   return 0.f;
  if (k < 100)  return Wo[k * 9 + m];
  if (k == 109) return bo[m];
  return 0.f;
}

// LDS-only barrier: do NOT drain vmcnt (global prefetch/stores stay in flight).
__device__ __forceinline__ void sync_lds() {
  asm volatile("s_waitcnt lgkmcnt(0)" ::: "memory");
  __builtin_amdgcn_s_barrier();
  asm volatile("" ::: "memory");
}

__global__ __launch_bounds__(NTHR, 4)
void lstm_fused(const float* __restrict__ g_input,
                const float* __restrict__ g_task,
                const float* __restrict__ g_Win,
                const float* __restrict__ g_bin,
                const float* __restrict__ g_Wtask,
                const float* __restrict__ g_btask,
                const float* __restrict__ g_Wx,
                const float* __restrict__ g_Wh,
                const float* __restrict__ g_bl,
                const float* __restrict__ g_Wout,
                const float* __restrict__ g_bout,
                float* __restrict__ g_out)
{
  __shared__ SM L;
  const int tid  = threadIdx.x;
  const int bg0  = blockIdx.x * 4;
  const int wv   = tid >> 6;        // wave id 0..15 (4 per SIMD)
  const int lane = tid & 63;
  const int q    = lane >> 4;       // MFMA k-quad
  const int nl   = lane & 15;       // A row m / B-D col n
  const int hi   = lane >> 4;       // D row group (unit-in-tile)
  const int xr_  = nl >> 2;         // replica -> tile select
  const int ab   = nl & 3;          // batch

  // ---- cooperative LDS fill: Y = 0 except k==109 -> 1.0 (bias slot) ----
  for (int i = tid; i < 2 * 4 * 144; i += NTHR)
    ((_Float16*)L.Y)[i] = ((i % 144) == 109) ? (_Float16)1.f : (_Float16)0.f;

  // ---- tile ownership: w0..11 = 2 tiles, w12 = 1, w15 = proj, w13/w14 = 0 ----
  const int NR    = (wv < 12) ? 2 : (wv == 12) ? 1 : 0;    // recurrent tiles
  const int NTF   = (wv == 15) ? 1 : NR;                   // fragment slots
  const int tbase = (wv < 12) ? wv * 2 : 24;

  // ---- A-fragments: weights, reg-stationary. m = nl = 4*Uin + gate. ----
  half8 Af[2][4];   // [ti][kc]; lane holds A[m=nl][k=kc*32+q*8+j]
  {
    const int gate = ab;
    const int Uin  = xr_;
#pragma unroll
    for (int ti = 0; ti < 2; ++ti) {
      if (ti < NTF) {
        const bool proj = (wv == 15);
        const int n = gate * 100 + (tbase + ti) * 4 + Uin;
#pragma unroll
        for (int kc = 0; kc < 4; ++kc) {
#pragma unroll
          for (int j = 0; j < 8; ++j) {
            const int k = kc * 32 + q * 8 + j;
            Af[ti][kc][j] = (_Float16)(proj ? wproj(k, nl, g_Wout, g_bout)
                                            : wld(k, n, g_Wh, g_Wx, g_bl));
          }
        }
      }
    }
  }

  // ---- activation ownership: lane (x,hi,b) -> unit (tbase + (x&1))*4 + hi ----
  const int aU = (tbase + ((NR == 2) ? (xr_ & 1) : 0)) * 4 + hi;
  float c_state = 0.f;

  // ---- wave-14 staging role: lanes 28..63 -> 36 items (b = sl/9, f = sl%9) ----
  const int sl  = lane - 28;
  const int stb = (sl >= 0) ? sl / 9 : 0;
  const int stf = (sl >= 0) ? sl % 9 : 0;
  float we_in[9], we_task[9], be_in = 0.f, be_task = 0.f;
  if (wv == 14) {
#pragma unroll
    for (int ff = 0; ff < 9; ++ff) {
      we_in[ff]   = g_Win[ff * 9 + stf];
      we_task[ff] = g_Wtask[ff * 9 + stf];
    }
    be_in = g_bin[stf]; be_task = g_btask[stf];
  }
  float xrA[9], xrB[9];   // prefetch buffers: xrB = odd times, xrA = even times

  auto LOADX = [&](float* xr, int tt) {
    const float* src = (tt < 512)
      ? g_input + ((long)(bg0 + stb) * 512 + tt) * 9
      : g_task  + ((long)(bg0 + stb) * 64 + (tt - 512)) * 9;
#pragma unroll
    for (int ff = 0; ff < 9; ++ff) xr[ff] = src[ff];
  };
  auto ENC9 = [&](const float* xr, const float (&w)[9], float b) -> float {
    float a0 = b, a1 = 0.f, a2 = 0.f;
    a0 = fmaf(xr[0], w[0], a0); a1 = fmaf(xr[1], w[1], a1); a2 = fmaf(xr[2], w[2], a2);
    a0 = fmaf(xr[3], w[3], a0); a1 = fmaf(xr[4], w[4], a1); a2 = fmaf(xr[5], w[5], a2);
    a0 = fmaf(xr[6], w[6], a0); a1 = fmaf(xr[7], w[7], a1); a2 = fmaf(xr[8], w[8], a2);
    return (a0 + a1) + a2;
  };
  auto ENCSTEP = [&](const float* xr, int tt) {
    float a;
    if (tt < 512) a = ENC9(xr, we_in, be_in);
    else          a = ENC9(xr, we_task, be_task);
    L.Y[tt & 1][stb][100 + stf] = (_Float16)fmaxf(a, 0.f);
  };
  // activation (R10 numerics): zv -> gates -> c -> h (f16 to LDS)
  auto ACT = [&](int p, const float* zv) {
    const float gi = fast_sigmoid(zv[0]);
    const float gf = fast_sigmoid(zv[1]);
    const float gg = fast_tanh(zv[2]);
    const float go = fast_sigmoid(zv[3]);
    c_state = fmaf(gf, c_state, gi * gg);
    L.Y[p ^ 1][ab][aU] = (_Float16)(go * fast_tanh(c_state));
  };
  // softmax over the projection D-fragment (w15 xr_==0 lanes: logits[4hi+r][ab])
  auto SMAX = [&](f32x4 v, int tout) {
    float e0 = __expf(v[0]), e1 = __expf(v[1]), e2 = __expf(v[2]), e3 = __expf(v[3]);
    if (hi == 2) { e1 = 0.f; e2 = 0.f; e3 = 0.f; }
    if (hi == 3) { e0 = 0.f; e1 = 0.f; e2 = 0.f; e3 = 0.f; }
    const float pl = (e0 + e1) + (e2 + e3);
    const float s1 = pl + __uint_as_float(__builtin_amdgcn_ds_swizzle(__float_as_uint(pl), 0x401F));
    const float ss = s1 + __shfl_xor(s1, 32, 64);
    const float rs = __builtin_amdgcn_rcpf(ss);
    if (hi < 3) {
      float* dst = g_out + ((long)(bg0 + ab) * 576 + tout) * 9 + 4 * hi;
      dst[0] = e0 * rs;
      if (hi < 2) { dst[1] = e1 * rs; dst[2] = e2 * rs; dst[3] = e3 * rs; }
    }
  };

  sync_lds();   // Y zero-fill visible

  // ---- prologue (wave 14): stage encoded s_0 into Y[0]; prefetch x(1),x(2) ----
  if (wv == 14 && sl >= 0) {
    float x0[9];
    LOADX(x0, 0);
    L.Y[0][stb][100 + stf] = (_Float16)fmaxf(ENC9(x0, we_in, be_in), 0.f);
    LOADX(xrB, 1);
    LOADX(xrA, 2);
  }
  sync_lds();

  // ---- main recurrence: ONE LDS-only barrier per step ----
  for (int t = 0; t < 576; ++t) {
    const int p = t & 1;
    half8 Bv[4];
    f32x4 acc[2];
    if (NTF > 0) {
      // -- B-operand: y rows, n = 4x+b -> each lane reads batch ab --
#pragma unroll
      for (int kc = 0; kc < 4; ++kc)
        Bv[kc] = *(const half8*)&L.Y[p][ab][kc * 32 + q * 8];
      // -- GEMM on matrix pipe (w15: projection tile) --
#pragma unroll
      for (int ti = 0; ti < 2; ++ti) {
        if (ti < NTF) {
          acc[ti] = (f32x4)0.f;
#pragma unroll
          for (int kc = 0; kc < 4; ++kc)
            acc[ti] = __builtin_amdgcn_mfma_f32_16x16x32_f16(Af[ti][kc], Bv[kc], acc[ti], 0, 0, 0);
        }
      }
    }
    // -- post-GEMM roles --
    if (NR > 0) {
      if (xr_ < NR) {                      // live replicas only (no dup writes)
        float zv[4];
#pragma unroll
        for (int g = 0; g < 4; ++g)
          zv[g] = (NR == 2 && (xr_ & 1)) ? acc[1][g] : acc[0][g];
        ACT(p, zv);
      }
    } else if (wv == 15) {
      if (xr_ == 0 && t > 0) SMAX(acc[0], t - 1);   // logits of h[t-1]
    } else if (wv == 14) {
      // -- staging: consume prefetched x(t+1), refill with x(t+3) --
      if (sl >= 0 && t + 1 < 576) {
        if (t & 1) { ENCSTEP(xrA, t + 1); if (t + 3 < 576) LOADX(xrA, t + 3); }
        else       { ENCSTEP(xrB, t + 1); if (t + 3 < 576) LOADX(xrB, t + 3); }
      }
    }
    sync_lds();
  }

  // ---- tail: projection + softmax for t=575 (h[575] in Y[0]) ----
  if (wv == 15) {
    half8 Bv[4];
#pragma unroll
    for (int kc = 0; kc < 4; ++kc)
      Bv[kc] = *(const half8*)&L.Y[0][ab][kc * 32 + q * 8];
    f32x4 a0 = (f32x4)0.f;
#pragma unroll
    for (int kc = 0; kc < 4; ++kc)
      a0 = __builtin_amdgcn_mfma_f32_16x16x32_f16(Af[0][kc], Bv[kc], a0, 0, 0, 0);
    if (xr_ == 0) SMAX(a0, 575);
  }
}

extern "C" void kernel_launch(void* const* d_in, const int* in_sizes, int n_in,
                              void* d_out, int out_size, void* d_ws, size_t ws_size,
                              hipStream_t stream) {
  const float* input  = (const float*)d_in[0];
  const float* task   = (const float*)d_in[1];
  const float* W_in   = (const float*)d_in[2];
  const float* b_in   = (const float*)d_in[3];
  const float* W_task = (const float*)d_in[4];
  const float* b_task = (const float*)d_in[5];
  const float* W_x    = (const float*)d_in[6];
  const float* W_h    = (const float*)d_in[7];
  const float* b_lstm = (const float*)d_in[8];
  const float* W_out  = (const float*)d_in[9];
  const float* b_out  = (const float*)d_in[10];
  float* out = (float*)d_out;

  lstm_fused<<<256, NTHR, 0, stream>>>(input, task, W_in, b_in, W_task, b_task,
                                       W_x, W_h, b_lstm, W_out, b_out, out);
}